// Round 7
// baseline (1962.483 us; speedup 1.0000x reference)
//
#include <hip/hip_runtime.h>
#include <hip/hip_cooperative_groups.h>

namespace cg = cooperative_groups;

// GAP-TV CASSI reconstruction, H=W=512, L=28, 12 iterations, sigma=0.5 Gaussian.
// Dispersion offsets resolve to dx[l]=l, dy[l]=0  (rint of s*cos(1deg), s*sin(1deg)).
#define HH 512
#define WW 512
#define LL 28
#define WP 539              // W + dx_max (27)
#define NPIX (HH * WP)      // 512*539 = 275968
#define NX (LL * HH * WW)   // 28*512*512

#define TX 64
#define TY 16
#define GB 7                // bands per tile group
#define NTILE (8 * 32 * 4)  // (W/TX) x (H/TY) x (L/GB) = 1024 tiles

// Single persistent cooperative kernel: init + 12 GAP iterations.
// Per iteration (one grid phase, one grid.sync at the end):
//   chores (grid-stride over NPIX): y1_out = y1_in + y - yb_rd ; zero yb_ze
//   tiles  (grid-stride over 1024): t-tile = (y1_in + y - yb_rd - yb_rd)*phi_inv in LDS;
//          per band: u = x + m*t ; 5x5 separable blur ; write x_next ; accum yb_ac (LDS->atomics)
// yb ring: read buf[it%3], accumulate buf[(it+1)%3] (pre-zeroed), zero buf[(it+2)%3].
__global__ __launch_bounds__(256, 4) void k_mega(
    const float* __restrict__ y, const float* __restrict__ mask,
    float* __restrict__ xOut,      // d_out == ping-pong W0 (final write lands here)
    float* __restrict__ xWs,       // ping-pong W1 (workspace)
    float* __restrict__ phi_inv,
    float* __restrict__ y1U, float* __restrict__ y1V,
    float* __restrict__ ybP, float* __restrict__ ybQ, float* __restrict__ ybR,
    float w0, float w1, float w2)
{
    cg::grid_group grid = cg::this_grid();
    const int tid = threadIdx.x;
    const int tx = tid & 63;
    const int ty = tid >> 6;
    const int nblk = gridDim.x;
    const int gthreads = nblk * 256;
    const int gtid = blockIdx.x * 256 + tid;

    __shared__ float msk[TY + 4][TX + 4];            // 20x68 mask tile (2-halo)
    __shared__ float tld[TY + 4][TX + 4 + GB - 1];   // 20x74 t tile (2-halo + band window)
    __shared__ float u[TY + 4][TX + 4];              // 20x68
    __shared__ float hb[TY + 4][TX];                 // 20x64
    __shared__ float ybl[TY][TX + GB - 1];           // 16x70 forward-scatter accumulator

    // ---------------- init ----------------
    // phi_inv = 1/max(phi_sum,1); yb0 = A(At(y)) = y * sum_l mask^2 (closed form); y1 = y; zero Q.
    for (int idx = gtid; idx < NPIX; idx += gthreads) {
        int i = idx / WP, jp = idx - i * WP;
        int lmin = jp - (WW - 1); if (lmin < 0) lmin = 0;
        int lmax = jp < (LL - 1) ? jp : (LL - 1);
        float s = 0.f, sq = 0.f;
        for (int l = lmin; l <= lmax; ++l) {
            float m = mask[i * WW + (jp - l)];
            s += m; sq = fmaf(m, m, sq);
        }
        phi_inv[idx] = 1.0f / fmaxf(s, 1.0f);
        float yv = y[idx];
        y1U[idx] = yv;
        ybP[idx] = yv * sq;
        ybQ[idx] = 0.f;
    }
    // x0 = At(y) into W0 (= xOut)
    for (int idx = gtid; idx < NX; idx += gthreads) {
        int l = idx / (HH * WW);
        int r = idx - l * HH * WW;      // r = i*512 + j
        int i = r >> 9, j = r & 511;
        xOut[idx] = y[i * WP + j + l] * mask[r];
    }
    grid.sync();

    float* xcur = xOut;
    float* xnxt = xWs;
    float* ybbuf[3] = {ybP, ybQ, ybR};

    for (int it = 0; it < 12; ++it) {
        const float* ybRd = ybbuf[it % 3];
        float* ybAc = ybbuf[(it + 1) % 3];
        float* ybZe = ybbuf[(it + 2) % 3];
        const float* y1in = (it & 1) ? y1V : y1U;
        float* y1out      = (it & 1) ? y1U : y1V;
        const bool last = (it == 11);

        // ---- chores: y1 ping-pong update + zero next-next yb (not needed after last iter) ----
        if (!last) {
            for (int idx = gtid; idx < NPIX; idx += gthreads) {
                float yb_ = ybRd[idx];
                y1out[idx] = y1in[idx] + y[idx] - yb_;
                ybZe[idx] = 0.f;
            }
        }

        // ---- tiles ----
        for (int tt = blockIdx.x; tt < NTILE; tt += nblk) {
            const int bj = (tt & 7) * TX;
            const int bi = ((tt >> 3) & 31) * TY;
            const int l0 = (tt >> 8) * GB;

            __syncthreads();   // protect LDS reused from previous tile

            // stage mask (20x68) and t (20x74): t = (y1in + y - yb - yb) * phi_inv
            #pragma unroll
            for (int k = 0; k < 5; ++k) {
                int r = ty + 4 * k;
                int gi = bi + r - 2;
                bool rok = (gi >= 0) & (gi < HH);
                int gj0 = bj + tx - 2;
                float m0 = 0.f;
                if (rok & (gj0 >= 0) & (gj0 < WW)) m0 = mask[gi * WW + gj0];
                msk[r][tx] = m0;
                if (tx < 4) {
                    int gj1 = bj + 64 + tx - 2;
                    float m1 = 0.f;
                    if (rok & (gj1 < WW)) m1 = mask[gi * WW + gj1];
                    msk[r][64 + tx] = m1;
                }
                int tg0 = bj + l0 - 2 + tx;
                float v0 = 0.f;
                if (rok & (tg0 >= 0) & (tg0 < WP)) {
                    int p = gi * WP + tg0;
                    float yb_ = ybRd[p];
                    float y1n = y1in[p] + y[p] - yb_;
                    v0 = (y1n - yb_) * phi_inv[p];
                }
                tld[r][tx] = v0;
                if (tx < 4 + GB - 1) {
                    int tg1 = tg0 + 64;
                    float v1 = 0.f;
                    if (rok & (tg1 >= 0) & (tg1 < WP)) {
                        int p = gi * WP + tg1;
                        float yb_ = ybRd[p];
                        float y1n = y1in[p] + y[p] - yb_;
                        v1 = (y1n - yb_) * phi_inv[p];
                    }
                    tld[r][64 + tx] = v1;
                }
            }
            if (!last) {
                #pragma unroll
                for (int k = 0; k < 4; ++k) {
                    int r = ty + 4 * k;
                    ybl[r][tx] = 0.f;
                    if (tx < GB - 1) ybl[r][64 + tx] = 0.f;
                }
            }
            __syncthreads();

            for (int l = l0; l < l0 + GB; ++l) {
                const float* xl = xcur + (size_t)l * HH * WW;
                const int dl = l - l0;
                // u = x + m * t  (2-halo, zero outside image)
                #pragma unroll
                for (int k = 0; k < 5; ++k) {
                    int r = ty + 4 * k;
                    int gi = bi + r - 2;
                    bool rok = (gi >= 0) & (gi < HH);
                    int gj0 = bj + tx - 2;
                    float v0 = 0.f;
                    if (rok & (gj0 >= 0) & (gj0 < WW))
                        v0 = fmaf(tld[r][tx + dl], msk[r][tx], xl[gi * WW + gj0]);
                    u[r][tx] = v0;
                    if (tx < 4) {
                        int gj1 = bj + 64 + tx - 2;
                        float v1 = 0.f;
                        if (rok & (gj1 < WW))
                            v1 = fmaf(tld[r][64 + tx + dl], msk[r][64 + tx], xl[gi * WW + gj1]);
                        u[r][64 + tx] = v1;
                    }
                }
                __syncthreads();
                // horizontal blur (20 rows)
                #pragma unroll
                for (int k = 0; k < 5; ++k) {
                    int r = ty + 4 * k;
                    hb[r][tx] = w2 * (u[r][tx] + u[r][tx + 4])
                              + w1 * (u[r][tx + 1] + u[r][tx + 3])
                              + w0 * u[r][tx + 2];
                }
                __syncthreads();
                // vertical blur + store x_next + forward-scatter accumulate
                #pragma unroll
                for (int k = 0; k < 4; ++k) {
                    int r = ty + 4 * k;
                    float o = w2 * (hb[r][tx] + hb[r + 4][tx])
                            + w1 * (hb[r + 1][tx] + hb[r + 3][tx])
                            + w0 * hb[r + 2][tx];
                    xnxt[((size_t)l * HH + bi + r) * WW + bj + tx] = o;
                    if (!last) ybl[r][tx + dl] += msk[r + 2][tx + 2] * o;
                }
                __syncthreads();
            }

            if (!last) {
                #pragma unroll
                for (int k = 0; k < 4; ++k) {
                    int r = ty + 4 * k;
                    atomicAdd(&ybAc[(bi + r) * WP + bj + l0 + tx], ybl[r][tx]);
                    if (tx < GB - 1)
                        atomicAdd(&ybAc[(bi + r) * WP + bj + l0 + 64 + tx], ybl[r][64 + tx]);
                }
            }
        }

        grid.sync();
        float* tmp = xcur; xcur = xnxt; xnxt = tmp;
    }
    // 12 swaps -> final write (it=11) landed in xOut == d_out.
}

extern "C" void kernel_launch(void* const* d_in, const int* in_sizes, int n_in,
                              void* d_out, int out_size, void* d_ws, size_t ws_size,
                              hipStream_t stream) {
    const float* y    = (const float*)d_in[0];   // [1, 512, 539]
    const float* mask = (const float*)d_in[1];   // [512, 512]

    float* xOut = (float*)d_out;                 // [1, 28, 512, 512]

    float* phi_inv = (float*)d_ws;               // NPIX
    float* y1U     = phi_inv + NPIX;             // NPIX
    float* y1V     = y1U + NPIX;                 // NPIX
    float* ybP     = y1V + NPIX;                 // NPIX
    float* ybQ     = ybP + NPIX;                 // NPIX
    float* ybR     = ybQ + NPIX;                 // NPIX
    float* xWs     = ybR + NPIX;                 // NX

    // Gaussian weights (sigma = 0.5, ksize = 5)
    float g1 = expf(-2.0f), g2 = expf(-8.0f);
    float gs = 1.0f + 2.0f * g1 + 2.0f * g2;
    float w0 = 1.0f / gs, w1 = g1 / gs, w2 = g2 / gs;

    // Deterministic, capture-safe sizing queries.
    int nCU = 256;
    hipDeviceGetAttribute(&nCU, hipDeviceAttributeMultiprocessorCount, 0);
    int perCU = 0;
    hipOccupancyMaxActiveBlocksPerMultiprocessor(&perCU, k_mega, 256, 0);
    int blocks = perCU * nCU;
    if (blocks > 1024) blocks = 1024;
    if (blocks < 256) blocks = 256;   // 1 block/CU always fits this kernel

    void* args[] = {(void*)&y, (void*)&mask, (void*)&xOut, (void*)&xWs,
                    (void*)&phi_inv, (void*)&y1U, (void*)&y1V,
                    (void*)&ybP, (void*)&ybQ, (void*)&ybR,
                    (void*)&w0, (void*)&w1, (void*)&w2};
    hipLaunchCooperativeKernel((const void*)k_mega, dim3(blocks), dim3(256),
                               args, 0, stream);
}

// Round 9
// 581.737 us; speedup vs baseline: 3.3735x; 3.3735x over previous
//
#include <hip/hip_runtime.h>
#include <hip/hip_fp16.h>

// GAP-TV CASSI reconstruction, H=W=512, L=28, 12 iterations, sigma=0.5 Gaussian.
// Dispersion offsets resolve to dx[l]=l, dy[l]=0 (rint of s*cos(1deg), s*sin(1deg)).
// Structure (R8): shallow, wide multi-kernel. Per iteration:
//   k_pix  (streaming): yb -> y1,t ; re-zero yb
//   k_band (7168 blocks, one band-tile each, 2 barriers): x' = blur(x + m*t),
//          yb += m*x' via direct coalesced atomics. x ping-pong stored fp16.
#define HH 512
#define WW 512
#define LL 28
#define WP 539              // W + dx_max (27)
#define NPIX (HH * WP)      // 275968
#define NX (LL * HH * WW)   // 7340032

#define TX 64
#define TY 16

// ---- setup: phi_inv = 1/max(sum_l m,1); y1 = y; yb0 = A(At(y)) = y*sum_l m^2 ----
__global__ __launch_bounds__(256) void k_setup(const float* __restrict__ y,
                                               const float* __restrict__ mask,
                                               float* __restrict__ phi_inv,
                                               float* __restrict__ y1,
                                               float* __restrict__ yb) {
    int idx = blockIdx.x * blockDim.x + threadIdx.x;
    if (idx >= NPIX) return;
    int i = idx / WP, jp = idx - i * WP;
    int lmin = jp - (WW - 1); if (lmin < 0) lmin = 0;
    int lmax = jp < (LL - 1) ? jp : (LL - 1);
    float s = 0.f, sq = 0.f;
    const float* mrow = mask + i * WW;
    for (int l = lmin; l <= lmax; ++l) {
        float m = mrow[jp - l];
        s += m; sq = fmaf(m, m, sq);
    }
    phi_inv[idx] = 1.0f / fmaxf(s, 1.0f);
    float yv = y[idx];
    y1[idx] = yv;
    yb[idx] = yv * sq;
}

// ---- x0 = At(y) in fp16 (2 elements/thread, half2 store) ----
__global__ __launch_bounds__(256) void k_xinit(const float* __restrict__ y,
                                               const float* __restrict__ mask,
                                               __half* __restrict__ x) {
    int idx = blockIdx.x * blockDim.x + threadIdx.x;   // NX/2 threads
    if (idx >= NX / 2) return;
    int p = idx * 2;
    int l = p / (HH * WW);
    int r = p - l * HH * WW;
    int i = r >> 9, j = r & 511;                       // j even
    const float* yrow = y + i * WP + l;
    const float* mrow = mask + i * WW;
    __half2 v = __floats2half2_rn(yrow[j] * mrow[j], yrow[j + 1] * mrow[j + 1]);
    *reinterpret_cast<__half2*>(x + p) = v;
}

// ---- per-iteration pixel step (float4): consume yb, update y1, produce t, re-zero yb ----
__global__ __launch_bounds__(256) void k_pix(const float* __restrict__ y,
                                             const float* __restrict__ phi_inv,
                                             float* __restrict__ y1,
                                             float* __restrict__ t,
                                             float* __restrict__ yb) {
    int idx = blockIdx.x * blockDim.x + threadIdx.x;
    if (idx >= NPIX / 4) return;
    float4 ybv = ((const float4*)yb)[idx];
    float4 yv  = ((const float4*)y)[idx];
    float4 y1v = ((const float4*)y1)[idx];
    float4 pv  = ((const float4*)phi_inv)[idx];
    float4 y1n, tv;
    y1n.x = y1v.x + yv.x - ybv.x;  tv.x = (y1n.x - ybv.x) * pv.x;
    y1n.y = y1v.y + yv.y - ybv.y;  tv.y = (y1n.y - ybv.y) * pv.y;
    y1n.z = y1v.z + yv.z - ybv.z;  tv.z = (y1n.z - ybv.z) * pv.z;
    y1n.w = y1v.w + yv.w - ybv.w;  tv.w = (y1n.w - ybv.w) * pv.w;
    ((float4*)y1)[idx] = y1n;
    ((float4*)t)[idx]  = tv;
    ((float4*)yb)[idx] = make_float4(0.f, 0.f, 0.f, 0.f);
}

// ---- per-band tile: x' = blur5x5(x + m*t); yb += m*x' (direct atomics). 2 barriers. ----
template <bool LAST>
__global__ __launch_bounds__(256) void k_band(const __half* __restrict__ xin,
                                              const float* __restrict__ t,
                                              const float* __restrict__ mask,
                                              void* __restrict__ xout,
                                              float* __restrict__ yb,
                                              float w0, float w1, float w2) {
    __shared__ float u[TY + 4][TX + 4];   // 20x68
    __shared__ float hb[TY + 4][TX];      // 20x64

    const int l  = blockIdx.z;
    const int bi = blockIdx.y * TY;
    const int bj = blockIdx.x * TX;
    const int tid = threadIdx.x;
    const int tx = tid & 63;
    const int ty = tid >> 6;
    const __half* xl = xin + (size_t)l * HH * WW;

    // phase 1: u = x + m*t with 2-halo (zero outside image)
    #pragma unroll
    for (int k = 0; k < 5; ++k) {
        int r = ty + 4 * k;                 // rows 0..19
        int gi = bi + r - 2;
        bool rok = (gi >= 0) & (gi < HH);
        int gj0 = bj + tx - 2;
        float v0 = 0.f;
        if (rok & (gj0 >= 0) & (gj0 < WW))
            v0 = fmaf(t[gi * WP + gj0 + l], mask[gi * WW + gj0],
                      __half2float(xl[gi * WW + gj0]));
        u[r][tx] = v0;
        if (tx < 4) {
            int gj1 = bj + 64 + tx - 2;
            float v1 = 0.f;
            if (rok & (gj1 < WW))
                v1 = fmaf(t[gi * WP + gj1 + l], mask[gi * WW + gj1],
                          __half2float(xl[gi * WW + gj1]));
            u[r][64 + tx] = v1;
        }
    }
    __syncthreads();

    // phase 2: horizontal blur, 20 rows
    #pragma unroll
    for (int k = 0; k < 5; ++k) {
        int r = ty + 4 * k;
        hb[r][tx] = w2 * (u[r][tx] + u[r][tx + 4])
                  + w1 * (u[r][tx + 1] + u[r][tx + 3])
                  + w0 * u[r][tx + 2];
    }
    __syncthreads();

    // phase 3: vertical blur + store + direct yb atomics (coalesced per wave)
    #pragma unroll
    for (int k = 0; k < 4; ++k) {
        int r = ty + 4 * k;                 // rows 0..15
        float o = w2 * (hb[r][tx] + hb[r + 4][tx])
                + w1 * (hb[r + 1][tx] + hb[r + 3][tx])
                + w0 * hb[r + 2][tx];
        int gi = bi + r, gj = bj + tx;
        if (LAST) {
            ((float*)xout)[((size_t)l * HH + gi) * WW + gj] = o;
        } else {
            ((__half*)xout)[((size_t)l * HH + gi) * WW + gj] = __float2half(o);
            atomicAdd(&yb[gi * WP + gj + l], mask[gi * WW + gj] * o);
        }
    }
}

extern "C" void kernel_launch(void* const* d_in, const int* in_sizes, int n_in,
                              void* d_out, int out_size, void* d_ws, size_t ws_size,
                              hipStream_t stream) {
    const float* y    = (const float*)d_in[0];   // [1, 512, 539]
    const float* mask = (const float*)d_in[1];   // [512, 512]
    float* out = (float*)d_out;                  // [1, 28, 512, 512] fp32

    float* phi_inv = (float*)d_ws;               // NPIX f32
    float* y1      = phi_inv + NPIX;             // NPIX f32
    float* t       = y1 + NPIX;                  // NPIX f32
    float* yb      = t + NPIX;                   // NPIX f32
    __half* xA     = (__half*)(yb + NPIX);       // NX f16 (ping-pong A)
    __half* xB     = xA + NX;                    // NX f16 (ping-pong B)

    // Gaussian weights (sigma = 0.5, ksize = 5)
    float g1 = expf(-2.0f), g2 = expf(-8.0f);
    float gs = 1.0f + 2.0f * g1 + 2.0f * g2;
    float w0 = 1.0f / gs, w1 = g1 / gs, w2 = g2 / gs;

    const dim3 bgrid(WW / TX, HH / TY, LL);      // 8 x 32 x 28 = 7168 blocks

    k_setup<<<(NPIX + 255) / 256, 256, 0, stream>>>(y, mask, phi_inv, y1, yb);
    k_xinit<<<(NX / 2 + 255) / 256, 256, 0, stream>>>(y, mask, xA);

    __half* cur = xA;
    __half* nxt = xB;
    for (int it = 0; it < 12; ++it) {
        k_pix<<<(NPIX / 4 + 255) / 256, 256, 0, stream>>>(y, phi_inv, y1, t, yb);
        if (it < 11) {
            k_band<false><<<bgrid, 256, 0, stream>>>(cur, t, mask, (void*)nxt, yb, w0, w1, w2);
            __half* tmp = cur; cur = nxt; nxt = tmp;
        } else {
            k_band<true><<<bgrid, 256, 0, stream>>>(cur, t, mask, (void*)out, yb, w0, w1, w2);
        }
    }
}

// Round 12
// 471.862 us; speedup vs baseline: 4.1590x; 1.2329x over previous
//
#include <hip/hip_runtime.h>
#include <hip/hip_fp16.h>

// GAP-TV CASSI reconstruction, H=W=512, L=28, 12 iterations, sigma=0.5 Gaussian.
// Dispersion offsets resolve to dx[l]=l, dy[l]=0 (rint of s*cos(1deg), s*sin(1deg)).
// R10 = R1 structure (best measured: gather-yb, no atomics, 2 kernels/iter)
//       + fp16 x ping-pong + unrolled interior gather in k_fwd.
#define HH 512
#define WW 512
#define LL 28
#define WP 539              // W + dx_max (27)
#define NPIX (HH * WP)      // 275968
#define NX (LL * HH * WW)   // 7340032

#define TX 64
#define TY 16

// ---- setup: phi_inv = 1/max(sum_l m,1); y1 = y ----
__global__ __launch_bounds__(256) void k_setup(const float* __restrict__ y,
                                               const float* __restrict__ mask,
                                               float* __restrict__ phi_inv,
                                               float* __restrict__ y1) {
    int idx = blockIdx.x * blockDim.x + threadIdx.x;
    if (idx >= NPIX) return;
    int i = idx / WP, jp = idx - i * WP;
    int lmin = jp - (WW - 1); if (lmin < 0) lmin = 0;
    int lmax = jp < (LL - 1) ? jp : (LL - 1);
    float s = 0.f;
    const float* mrow = mask + i * WW;
    for (int l = lmin; l <= lmax; ++l) s += mrow[jp - l];
    phi_inv[idx] = 1.0f / fmaxf(s, 1.0f);
    y1[idx] = y[idx];
}

// ---- x0 = At(y) in fp16 (2 elements/thread, half2 store) ----
__global__ __launch_bounds__(256) void k_xinit(const float* __restrict__ y,
                                               const float* __restrict__ mask,
                                               __half* __restrict__ x) {
    int idx = blockIdx.x * blockDim.x + threadIdx.x;   // NX/2 threads
    if (idx >= NX / 2) return;
    int p = idx * 2;
    int l = p / (HH * WW);
    int r = p - l * HH * WW;
    int i = r >> 9, j = r & 511;                       // j even
    const float* yrow = y + i * WP + l;
    const float* mrow = mask + i * WW;
    __half2 v = __floats2half2_rn(yrow[j] * mrow[j], yrow[j + 1] * mrow[j + 1]);
    *reinterpret_cast<__half2*>(x + p) = v;
}

// ---- per-iter step 1 (fused, gather): yb = A(x) in-register; y1 += y - yb; t = (y1-yb)*phi_inv ----
__global__ __launch_bounds__(256) void k_fwd(const __half* __restrict__ x,
                                             const float* __restrict__ mask,
                                             const float* __restrict__ y,
                                             const float* __restrict__ phi_inv,
                                             float* __restrict__ y1,
                                             float* __restrict__ t) {
    int idx = blockIdx.x * blockDim.x + threadIdx.x;
    if (idx >= NPIX) return;
    int i = idx / WP, jp = idx - i * WP;
    const __half* xr = x + i * WW;           // + l*HH*WW + (jp-l)
    float yb = 0.f;
    if (jp >= LL - 1 && jp < WW) {
        // interior: all 28 bands valid, compile-time unrolled
        const float* mrow = mask + i * WW + jp;
        #pragma unroll
        for (int l = 0; l < LL; ++l)
            yb = fmaf(mrow[-l], __half2float(xr[(size_t)l * HH * WW + jp - l]), yb);
    } else {
        int lmin = jp - (WW - 1); if (lmin < 0) lmin = 0;
        int lmax = jp < (LL - 1) ? jp : (LL - 1);
        const float* mrow = mask + i * WW;
        for (int l = lmin; l <= lmax; ++l)
            yb = fmaf(mrow[jp - l], __half2float(xr[(size_t)l * HH * WW + jp - l]), yb);
    }
    float y1n = y1[idx] + y[idx] - yb;
    y1[idx] = y1n;
    t[idx] = (y1n - yb) * phi_inv[idx];
}

// ---- per-iter step 2: xo = blur5x5(x + m*t) per band tile; 2 barriers, no atomics ----
template <bool LAST>
__global__ __launch_bounds__(256) void k_upblur(const __half* __restrict__ xin,
                                                const float* __restrict__ t,
                                                const float* __restrict__ mask,
                                                void* __restrict__ xout,
                                                float w0, float w1, float w2) {
    __shared__ float u[TY + 4][TX + 4];   // 20x68
    __shared__ float hb[TY + 4][TX];      // 20x64

    const int l  = blockIdx.z;
    const int bi = blockIdx.y * TY;
    const int bj = blockIdx.x * TX;
    const int tid = threadIdx.x;
    const int tx = tid & 63;
    const int ty = tid >> 6;
    const __half* xl = xin + (size_t)l * HH * WW;

    // phase 1: u = x + m*t with 2-halo (zero outside image)
    #pragma unroll
    for (int k = 0; k < 5; ++k) {
        int r = ty + 4 * k;                 // rows 0..19
        int gi = bi + r - 2;
        bool rok = (gi >= 0) & (gi < HH);
        int gj0 = bj + tx - 2;
        float v0 = 0.f;
        if (rok & (gj0 >= 0) & (gj0 < WW))
            v0 = fmaf(t[gi * WP + gj0 + l], mask[gi * WW + gj0],
                      __half2float(xl[gi * WW + gj0]));
        u[r][tx] = v0;
        if (tx < 4) {
            int gj1 = bj + 64 + tx - 2;
            float v1 = 0.f;
            if (rok & (gj1 < WW))
                v1 = fmaf(t[gi * WP + gj1 + l], mask[gi * WW + gj1],
                          __half2float(xl[gi * WW + gj1]));
            u[r][64 + tx] = v1;
        }
    }
    __syncthreads();

    // phase 2: horizontal blur, 20 rows
    #pragma unroll
    for (int k = 0; k < 5; ++k) {
        int r = ty + 4 * k;
        hb[r][tx] = w2 * (u[r][tx] + u[r][tx + 4])
                  + w1 * (u[r][tx + 1] + u[r][tx + 3])
                  + w0 * u[r][tx + 2];
    }
    __syncthreads();

    // phase 3: vertical blur + store
    #pragma unroll
    for (int k = 0; k < 4; ++k) {
        int r = ty + 4 * k;                 // rows 0..15
        float o = w2 * (hb[r][tx] + hb[r + 4][tx])
                + w1 * (hb[r + 1][tx] + hb[r + 3][tx])
                + w0 * hb[r + 2][tx];
        size_t p = ((size_t)l * HH + bi + r) * WW + bj + tx;
        if (LAST) ((float*)xout)[p] = o;
        else      ((__half*)xout)[p] = __float2half(o);
    }
}

extern "C" void kernel_launch(void* const* d_in, const int* in_sizes, int n_in,
                              void* d_out, int out_size, void* d_ws, size_t ws_size,
                              hipStream_t stream) {
    const float* y    = (const float*)d_in[0];   // [1, 512, 539]
    const float* mask = (const float*)d_in[1];   // [512, 512]
    float* out = (float*)d_out;                  // [1, 28, 512, 512] fp32

    float* phi_inv = (float*)d_ws;               // NPIX f32
    float* y1      = phi_inv + NPIX;             // NPIX f32
    float* t       = y1 + NPIX;                  // NPIX f32
    __half* xA     = (__half*)(t + NPIX);        // NX f16 (ping-pong A)
    __half* xB     = xA + NX;                    // NX f16 (ping-pong B)

    // Gaussian weights (sigma = 0.5, ksize = 5)
    float g1 = expf(-2.0f), g2 = expf(-8.0f);
    float gs = 1.0f + 2.0f * g1 + 2.0f * g2;
    float w0 = 1.0f / gs, w1 = g1 / gs, w2 = g2 / gs;

    const dim3 bgrid(WW / TX, HH / TY, LL);      // 8 x 32 x 28 = 7168 blocks

    k_setup<<<(NPIX + 255) / 256, 256, 0, stream>>>(y, mask, phi_inv, y1);
    k_xinit<<<(NX / 2 + 255) / 256, 256, 0, stream>>>(y, mask, xA);

    __half* cur = xA;
    __half* nxt = xB;
    for (int it = 0; it < 12; ++it) {
        k_fwd<<<(NPIX + 255) / 256, 256, 0, stream>>>(cur, mask, y, phi_inv, y1, t);
        if (it < 11) {
            k_upblur<false><<<bgrid, 256, 0, stream>>>(cur, t, mask, (void*)nxt, w0, w1, w2);
            __half* tmp = cur; cur = nxt; nxt = tmp;
        } else {
            k_upblur<true><<<bgrid, 256, 0, stream>>>(cur, t, mask, (void*)out, w0, w1, w2);
        }
    }
}